// Round 4
// baseline (44.577 us; speedup 1.0000x reference)
//
#include <hip/hip_runtime.h>
#include <hip/hip_bf16.h>

// Fast exp2 -> single v_exp_f32
#if defined(__has_builtin)
#if __has_builtin(__builtin_amdgcn_exp2f)
#define FAST_EXP2(x) __builtin_amdgcn_exp2f(x)
#endif
#endif
#ifndef FAST_EXP2
#define FAST_EXP2(x) exp2f(x)
#endif

#define N_TRAIN 8192
#define BSZ 4096
#define NOUT (BSZ * 3)      // 12288
#define BLK 256
#define NS  128             // n-segments (compile-time)
#define NBB 16              // b-blocks of 256
#define NB  (N_TRAIN / NS)  // 64 train points per segment

// ---------------------------------------------------------------------------
// prep: per train point n, z = W @ train_X[n]:
//   TB[2n]   = { c*z0^2, c*z1^2, c*z2^2, Y[n] }
//   TB[2n+1] = { -2c*z0, -2c*z1, -2c*z2, 0 }
// per batch point b: XW[b] = (xw0, xw1, xw2, 0), xw = W @ x[b].
// c = -log2(e)/(2h^2). The dropped exp2(c*xw^2) factor cancels in num/den.
// ---------------------------------------------------------------------------
__global__ __launch_bounds__(BLK) void prep_k(
    const float4* __restrict__ x4,    // [4096]
    const float4* __restrict__ tX4,   // [8192]
    const float*  __restrict__ Y,     // [8192]
    const float*  __restrict__ W,     // [3][4]
    const float*  __restrict__ hptr,  // [1]
    float4* __restrict__ TB,          // [8192][2]
    float4* __restrict__ XW)          // [4096]
{
    int idx = blockIdx.x * BLK + threadIdx.x;
    float h = hptr[0];
    float c = -0.72134752044448170368f / (h * h);  // -log2(e)/2 / h^2

    const float4* Wv = (const float4*)W;
    float4 w0 = Wv[0], w1 = Wv[1], w2 = Wv[2];

    if (idx < N_TRAIN) {
        float4 t = tX4[idx];
        float z0 = t.x * w0.x + t.y * w0.y + t.z * w0.z + t.w * w0.w;
        float z1 = t.x * w1.x + t.y * w1.y + t.z * w1.z + t.w * w1.w;
        float z2 = t.x * w2.x + t.y * w2.y + t.z * w2.z + t.w * w2.w;
        TB[2 * idx]     = make_float4(c * z0 * z0, c * z1 * z1, c * z2 * z2, Y[idx]);
        TB[2 * idx + 1] = make_float4(-2.f * c * z0, -2.f * c * z1, -2.f * c * z2, 0.f);
    } else {
        int b = idx - N_TRAIN;  // < 4096
        float4 t = x4[b];
        float x0 = t.x * w0.x + t.y * w0.y + t.z * w0.z + t.w * w0.w;
        float x1 = t.x * w1.x + t.y * w1.y + t.z * w1.z + t.w * w1.w;
        float x2 = t.x * w2.x + t.y * w2.y + t.z * w2.z + t.w * w2.w;
        XW[b] = make_float4(x0, x1, x2, 0.f);
    }
}

// ---------------------------------------------------------------------------
// main: 2048 blocks = 16 b-blocks x 128 segments -> 8 blocks/CU = 32 waves/CU
// (full occupancy; this is the latency-hiding fix — R3 ran at 2 waves/SIMD
// and paid one L1-latency per iteration). Thread owns one batch point; per
// train point n: two wave-uniform 16B loads, then per dim:
// 1 fma (arg) + 1 exp2 + 1 add (den) + 1 fma (num). No LDS.
// Partials layout [seg][d][4096] -> fully coalesced stores.
// ---------------------------------------------------------------------------
__global__ __launch_bounds__(BLK, 8) void kde_k(
    const float4* __restrict__ TB,   // [8192][2]
    const float4* __restrict__ XW,   // [4096]
    float* __restrict__ NP,          // [NS][3][4096]
    float* __restrict__ DP)          // [NS][3][4096]
{
    int tid  = threadIdx.x;
    int bblk = blockIdx.x & (NBB - 1);   // 16 b-blocks (fast-varying: same seg
    int seg  = blockIdx.x >> 4;          //   on neighboring blocks -> L2 reuse)
    int n0   = seg * NB;
    int b    = (bblk << 8) + tid;

    float4 xw = XW[b];
    float num0 = 0.f, num1 = 0.f, num2 = 0.f;
    float den0 = 0.f, den1 = 0.f, den2 = 0.f;

    #pragma unroll 4
    for (int t = 0; t < NB; ++t) {
        int n = n0 + t;                 // wave-uniform
        float4 a  = TB[2 * n];          // A0 A1 A2 Y
        float4 bb = TB[2 * n + 1];      // B0 B1 B2 -

        float e0 = FAST_EXP2(fmaf(bb.x, xw.x, a.x));
        float e1 = FAST_EXP2(fmaf(bb.y, xw.y, a.y));
        float e2 = FAST_EXP2(fmaf(bb.z, xw.z, a.z));
        den0 += e0;
        den1 += e1;
        den2 += e2;
        num0 = fmaf(e0, a.w, num0);
        num1 = fmaf(e1, a.w, num1);
        num2 = fmaf(e2, a.w, num2);
    }

    size_t sb = (size_t)seg * NOUT + b;
    NP[sb]           = num0;
    NP[sb + BSZ]     = num1;
    NP[sb + 2 * BSZ] = num2;
    DP[sb]           = den0;
    DP[sb + BSZ]     = den1;
    DP[sb + 2 * BSZ] = den2;
}

// ---------------------------------------------------------------------------
// reduce: 192 blocks; block owns 64 output elements x all 128 segments.
// Thread (o = tid&63, w = tid>>6): sums segments s = w, w+4, ... (32 iters,
// fully unrolled, coalesced 64-lane rows), then 4-wave LDS tree + divide.
// ---------------------------------------------------------------------------
__global__ __launch_bounds__(BLK) void reduce_k(
    const float* __restrict__ NP,
    const float* __restrict__ DP,
    float* __restrict__ out)
{
    __shared__ float sN[4][64];
    __shared__ float sD[4][64];

    int o = threadIdx.x & 63;
    int w = threadIdx.x >> 6;            // wave index 0..3
    int t = blockIdx.x * 64 + o;         // output element, < 12288

    float n = 0.f, d = 0.f;
    #pragma unroll
    for (int i = 0; i < NS / 4; ++i) {
        int s = w + i * 4;
        n += NP[(size_t)s * NOUT + t];
        d += DP[(size_t)s * NOUT + t];
    }
    sN[w][o] = n;
    sD[w][o] = d;
    __syncthreads();

    if (threadIdx.x < 64) {
        float nn = sN[0][o] + sN[1][o] + sN[2][o] + sN[3][o];
        float dd = sD[0][o] + sD[1][o] + sD[2][o] + sD[3][o];
        int b  = t & (BSZ - 1);
        int di = t >> 12;
        out[b * 3 + di] = nn / dd;
    }
}

extern "C" void kernel_launch(void* const* d_in, const int* in_sizes, int n_in,
                              void* d_out, int out_size, void* d_ws, size_t ws_size,
                              hipStream_t stream) {
    const float* x   = (const float*)d_in[0];  // [4096,4]
    const float* tX  = (const float*)d_in[1];  // [8192,4]
    const float* Y   = (const float*)d_in[2];  // [8192]
    const float* W   = (const float*)d_in[3];  // [3,4]
    const float* h   = (const float*)d_in[4];  // [1]
    float* out = (float*)d_out;                // [4096,3]

    // ws layout: TB [8192][2] float4 (256 KB) | XW [4096] float4 (64 KB)
    //            NP [NS][12288] f32 (6.3 MB) | DP [NS][12288] f32 (6.3 MB)
    float4* TB = (float4*)d_ws;
    float4* XW = TB + 2 * N_TRAIN;
    float*  NP = (float*)(XW + BSZ);
    float*  DP = NP + (size_t)NS * NOUT;

    prep_k<<<(N_TRAIN + BSZ) / BLK, BLK, 0, stream>>>(
        (const float4*)x, (const float4*)tX, Y, W, h, TB, XW);

    kde_k<<<NBB * NS, BLK, 0, stream>>>(TB, XW, NP, DP);

    reduce_k<<<NOUT / 64, BLK, 0, stream>>>(NP, DP, out);
}